// Round 1
// baseline (162.211 us; speedup 1.0000x reference)
//
#include <hip/hip_runtime.h>
#include <hip/hip_bf16.h>

typedef unsigned short u16;
typedef __attribute__((ext_vector_type(8))) short bf16x8;
typedef __attribute__((ext_vector_type(4))) float f32x4;

#define BDIM 4096
#define DDIM 1024
#define UDIM 1024
#define NE 8
#define NDIM 8192  // U*E

__device__ __forceinline__ u16 f2bf(float f) {
    unsigned int u = __float_as_uint(f);
    u += 0x7fffu + ((u >> 16) & 1u);   // round-to-nearest-even
    return (u16)(u >> 16);
}

__device__ __forceinline__ void gload_lds16(const u16* g, u16* lds) {
    __builtin_amdgcn_global_load_lds(
        (const __attribute__((address_space(1))) void*)g,
        (__attribute__((address_space(3))) void*)lds, 16, 0, 0);
}

// ---------------- pre-pass: x f32 -> bf16 ----------------
__global__ __launch_bounds__(256) void convert_x_kernel(
    const float* __restrict__ in, u16* __restrict__ out, int n4)
{
    int i = blockIdx.x * 256 + threadIdx.x;
    if (i < n4) {
        float4 v = ((const float4*)in)[i];
        ushort4 o;
        o.x = f2bf(v.x); o.y = f2bf(v.y); o.z = f2bf(v.z); o.w = f2bf(v.w);
        ((ushort4*)out)[i] = o;
    }
}

// ---------------- pre-pass: mu [D][N] f32 -> mu_t [N][D] bf16 (tiled transpose) ----------------
__global__ __launch_bounds__(256) void convert_mu_t_kernel(
    const float* __restrict__ mu, u16* __restrict__ mut)
{
    __shared__ u16 tile[64 * 66];  // pad 66: phase-2 lane stride 8 rows -> 2-way bank alias (free)
    const int n0 = blockIdx.x * 64;
    const int d0 = blockIdx.y * 64;
    const int tid = threadIdx.x;
    const int nl = tid & 63;
#pragma unroll
    for (int i = 0; i < 16; ++i) {
        int dl = i * 4 + (tid >> 6);
        tile[dl * 66 + nl] = f2bf(mu[(size_t)(d0 + dl) * NDIM + n0 + nl]);
    }
    __syncthreads();
#pragma unroll
    for (int issue = 0; issue < 2; ++issue) {
        int nloc = issue * 32 + (tid >> 3);
        int d8 = (tid & 7) * 8;
        uint4 o;
        u16* tp = (u16*)&o;
#pragma unroll
        for (int i = 0; i < 8; ++i) tp[i] = tile[(d8 + i) * 66 + nloc];
        *(uint4*)&mut[(size_t)(n0 + nloc) * DDIM + d0 + d8] = o;
    }
}

// ---------------- pre-pass: se[n] = softplus(rho)*eps ----------------
__global__ __launch_bounds__(256) void prep_se_kernel(
    const float* __restrict__ rho, const float* __restrict__ eps,
    float* __restrict__ se, int n)
{
    int i = blockIdx.x * 256 + threadIdx.x;
    if (i < n) {
        float r = rho[i];
        se[i] = log1pf(expf(r)) * eps[i];
    }
}

// ---------------- gating: logits -> softmax -> top2 renorm; also xsum ----------------
__global__ __launch_bounds__(256) void gating_kernel(
    const float* __restrict__ x, const float* __restrict__ gk,
    const float* __restrict__ gb, float* __restrict__ gw,
    float* __restrict__ xsum)
{
    const int b = blockIdx.x * 4 + (threadIdx.x >> 6);
    const int lane = threadIdx.x & 63;
    float acc[8] = {0.f,0.f,0.f,0.f,0.f,0.f,0.f,0.f};
    float xs = 0.f;
    for (int d = lane; d < DDIM; d += 64) {
        float xv = x[(size_t)b * DDIM + d];
        xs += xv;
        const float4* g4 = (const float4*)&gk[d * NE];
        float4 g0 = g4[0], g1 = g4[1];
        acc[0] += xv * g0.x; acc[1] += xv * g0.y; acc[2] += xv * g0.z; acc[3] += xv * g0.w;
        acc[4] += xv * g1.x; acc[5] += xv * g1.y; acc[6] += xv * g1.z; acc[7] += xv * g1.w;
    }
#pragma unroll
    for (int off = 32; off >= 1; off >>= 1) {
        xs += __shfl_xor(xs, off);
#pragma unroll
        for (int e = 0; e < 8; ++e) acc[e] += __shfl_xor(acc[e], off);
    }
    if (lane == 0) {
        float lg[8];
#pragma unroll
        for (int e = 0; e < 8; ++e) lg[e] = acc[e] + gb[e];
        int i1 = 0;
#pragma unroll
        for (int e = 1; e < 8; ++e) if (lg[e] > lg[i1]) i1 = e;   // first-occurrence argmax (matches top_k tie rule)
        int i2 = (i1 == 0) ? 1 : 0;
#pragma unroll
        for (int e = 0; e < 8; ++e) {
            if (e == i1 || e == i2) continue;
            if (lg[e] > lg[i2]) i2 = e;
        }
        // renormalized top-2 softmax == softmax over {l1, l2} (exact)
        float p1 = 1.f / (1.f + expf(lg[i2] - lg[i1]));
        float out[8] = {0.f,0.f,0.f,0.f,0.f,0.f,0.f,0.f};
        out[i1] = p1; out[i2] = 1.f - p1;
#pragma unroll
        for (int e = 0; e < 8; ++e) gw[b * NE + e] = out[e];
        xsum[b] = xs;
    }
}

// ---------------- main: C = Xb @ mu^T fused with gate-weighted e-reduction ----------------
// m97 structure: 128x128 tile, BK=64, 4 waves (2x2), global_load_lds w16, 2-barrier K-loop.
__global__ __launch_bounds__(256) void gemm_moe_kernel(
    const u16* __restrict__ Xb,    // [4096][1024] bf16
    const u16* __restrict__ Wt,    // [8192][1024] bf16 (mu transposed: row n = (u*8+e), col d)
    const float* __restrict__ gw,  // [4096][8]
    const float* __restrict__ xsum,// [4096]
    const float* __restrict__ se,  // [8192] flat (u*8+e)
    const float* __restrict__ biasv,// [8192] flat
    float* __restrict__ y)         // [4096][1024]
{
    __shared__ u16 As[128 * 64];
    __shared__ u16 Bs[128 * 64];

    const int tid  = threadIdx.x;
    const int lane = tid & 63;
    const int wid  = tid >> 6;
    const int wm = wid >> 1, wn = wid & 1;
    const int brow = blockIdx.y * 128;
    const int bcol = blockIdx.x * 128;
    const int l15 = lane & 15;
    const int l4  = lane >> 4;

    f32x4 acc[4][4] = {};

    const int stg_r  = tid >> 3;        // 0..31
    const int stg_c8 = (tid & 7) * 8;   // 0..56

    for (int kk = 0; kk < DDIM; kk += 64) {
#pragma unroll
        for (int it = 0; it < 4; ++it) {
            int r = it * 32 + stg_r;
            gload_lds16(&Xb[(size_t)(brow + r) * DDIM + kk + stg_c8], &As[r * 64 + stg_c8]);
            gload_lds16(&Wt[(size_t)(bcol + r) * DDIM + kk + stg_c8], &Bs[r * 64 + stg_c8]);
        }
        __syncthreads();
#pragma unroll
        for (int k2 = 0; k2 < 2; ++k2) {
            bf16x8 av[4], bv[4];
#pragma unroll
            for (int m = 0; m < 4; ++m)
                av[m] = *(const bf16x8*)&As[(wm * 64 + m * 16 + l15) * 64 + k2 * 32 + l4 * 8];
#pragma unroll
            for (int n = 0; n < 4; ++n)
                bv[n] = *(const bf16x8*)&Bs[(wn * 64 + n * 16 + l15) * 64 + k2 * 32 + l4 * 8];
#pragma unroll
            for (int m = 0; m < 4; ++m)
#pragma unroll
                for (int n = 0; n < 4; ++n)
                    acc[m][n] = __builtin_amdgcn_mfma_f32_16x16x32_bf16(av[m], bv[n], acc[m][n], 0, 0, 0);
        }
        __syncthreads();
    }

    // Epilogue: y[b,u] = sum_e gw[b,e]*(C[b,u*8+e] + xsum[b]*se[u,e] + bias[u,e])
    // C/D layout (m89-verified): N-index = lane&15, M-index = (lane>>4)*4 + reg.
    // The 8 experts of one u live in 8 adjacent lanes -> shfl_xor {1,2,4} reduce.
#pragma unroll
    for (int n = 0; n < 4; ++n) {
        int c = bcol + wn * 64 + n * 16 + l15;  // global column = u*8+e
        int e = c & 7;
        int u = c >> 3;
        float sec = se[c];
        float bc  = biasv[c];
#pragma unroll
        for (int m = 0; m < 4; ++m) {
            int r0 = brow + wm * 64 + m * 16 + l4 * 4;
#pragma unroll
            for (int j = 0; j < 4; ++j) {
                int r = r0 + j;
                float val = acc[m][n][j] + xsum[r] * sec + bc;
                float wv = gw[r * NE + e] * val;
                wv += __shfl_xor(wv, 1);
                wv += __shfl_xor(wv, 2);
                wv += __shfl_xor(wv, 4);
                if ((lane & 7) == 0) y[(size_t)r * UDIM + u] = wv;
            }
        }
    }
}

extern "C" void kernel_launch(void* const* d_in, const int* in_sizes, int n_in,
                              void* d_out, int out_size, void* d_ws, size_t ws_size,
                              hipStream_t stream) {
    const float* x    = (const float*)d_in[0];
    const float* mu   = (const float*)d_in[1];
    const float* rho  = (const float*)d_in[2];
    const float* bias = (const float*)d_in[3];
    const float* gk   = (const float*)d_in[4];
    const float* gb   = (const float*)d_in[5];
    const float* eps  = (const float*)d_in[6];
    float* y = (float*)d_out;

    char* ws = (char*)d_ws;
    // layout (16B aligned):
    u16*  mu_t = (u16*)ws;                          // 8192*1024*2 = 16,777,216
    u16*  xb   = (u16*)(ws + 16777216);             // 4096*1024*2 =  8,388,608
    float* gwp = (float*)(ws + 25165824);           // 4096*8*4    =    131,072
    float* xsp = (float*)(ws + 25296896);           // 4096*4      =     16,384
    float* sep = (float*)(ws + 25313280);           // 8192*4      =     32,768
    if (ws_size < 25346048) return;                 // need ~24.2 MB scratch

    convert_x_kernel<<<dim3(4096), dim3(256), 0, stream>>>(x, xb, (BDIM * DDIM) / 4);
    convert_mu_t_kernel<<<dim3(NDIM / 64, DDIM / 64), dim3(256), 0, stream>>>(mu, mu_t);
    prep_se_kernel<<<dim3(32), dim3(256), 0, stream>>>(rho, eps, sep, NDIM);
    gating_kernel<<<dim3(BDIM / 4), dim3(256), 0, stream>>>(x, gk, gb, gwp, xsp);
    gemm_moe_kernel<<<dim3(NDIM / 128, BDIM / 128), dim3(256), 0, stream>>>(
        xb, mu_t, gwp, xsp, sep, bias, y);
}